// Round 6
// baseline (306.402 us; speedup 1.0000x reference)
//
#include <hip/hip_runtime.h>
#include <hip/hip_bf16.h>
#include <math.h>

#define B_ 16
#define S_ 2048
#define D_ 256
#define H_ 512
#define NS_ 64
#define N2 4096
#define M_ (B_*S_)
#define XP(i) ((i) + ((i) >> 4))

typedef float f32x4 __attribute__((ext_vector_type(4)));
typedef short bf16x8 __attribute__((ext_vector_type(8)));

__device__ __forceinline__ unsigned short f2bf(float x) {
    __hip_bfloat16 h = __float2bfloat16(x);
    return *reinterpret_cast<unsigned short*>(&h);
}

__device__ __forceinline__ float gelu_f(float y) {
    float u = y + 0.044715f*y*y*y;
    return y / (1.0f + __builtin_exp2f(-2.3022082f * u));
}

// hw trig on revolutions (inputs pre-reduced to [0,1))
__device__ __forceinline__ float cos_rev(float r) { return __builtin_amdgcn_cosf(r); }
__device__ __forceinline__ float sin_rev(float r) { return __builtin_amdgcn_sinf(r); }

// ---------------- 16-point DFT in registers (2 x radix-4) ----------------
// MODE 0: full.  MODE 1: inputs 8..15 are zero.  MODE 2: only outputs 0..7 needed.
template<bool INV, int MODE>
__device__ __forceinline__ void dft16(float* xr, float* xi) {
    const float SGN = INV ? 1.0f : -1.0f;
    constexpr float W16R[4][4] = {
        {1.f, 1.f, 1.f, 1.f},
        {1.f,  0.92387953251128674f,  0.70710678118654757f,  0.38268343236508984f},
        {1.f,  0.70710678118654757f,  0.0f,                 -0.70710678118654746f},
        {1.f,  0.38268343236508984f, -0.70710678118654746f, -0.92387953251128674f}};
    constexpr float W16I[4][4] = {
        {0.f, 0.f, 0.f, 0.f},
        {0.f, -0.38268343236508978f, -0.70710678118654746f, -0.92387953251128674f},
        {0.f, -0.70710678118654746f, -1.0f,                 -0.70710678118654757f},
        {0.f, -0.92387953251128674f, -0.70710678118654757f,  0.38268343236508967f}};
    float tr[16], ti[16];
    #pragma unroll
    for (int n0 = 0; n0 < 4; ++n0) {
        if (MODE == 1) {
            float ar = xr[n0],   ai = xi[n0];
            float br = xr[n0+4], bi = xi[n0+4];
            tr[0*4+n0] = ar + br;        ti[0*4+n0] = ai + bi;
            tr[2*4+n0] = ar - br;        ti[2*4+n0] = ai - bi;
            tr[1*4+n0] = ar - SGN*bi;    ti[1*4+n0] = ai + SGN*br;
            tr[3*4+n0] = ar + SGN*bi;    ti[3*4+n0] = ai - SGN*br;
        } else {
            float ar = xr[n0],    ai = xi[n0];
            float br = xr[n0+4],  bi = xi[n0+4];
            float cr = xr[n0+8],  ci = xi[n0+8];
            float dr = xr[n0+12], di = xi[n0+12];
            float sacr = ar+cr, saci = ai+ci;
            float dacr = ar-cr, daci = ai-ci;
            float sbdr = br+dr, sbdi = bi+di;
            float dbdr = br-dr, dbdi = bi-di;
            tr[0*4+n0] = sacr + sbdr;      ti[0*4+n0] = saci + sbdi;
            tr[2*4+n0] = sacr - sbdr;      ti[2*4+n0] = saci - sbdi;
            tr[1*4+n0] = dacr - SGN*dbdi;  ti[1*4+n0] = daci + SGN*dbdr;
            tr[3*4+n0] = dacr + SGN*dbdi;  ti[3*4+n0] = daci - SGN*dbdr;
        }
    }
    #pragma unroll
    for (int kl = 1; kl < 4; ++kl) {
        #pragma unroll
        for (int n0 = 1; n0 < 4; ++n0) {
            float wr = W16R[kl][n0];
            float wi = INV ? -W16I[kl][n0] : W16I[kl][n0];
            float pr = tr[kl*4+n0], pi = ti[kl*4+n0];
            tr[kl*4+n0] = pr*wr - pi*wi;
            ti[kl*4+n0] = pr*wi + pi*wr;
        }
    }
    #pragma unroll
    for (int kl = 0; kl < 4; ++kl) {
        float ar = tr[kl*4+0], ai = ti[kl*4+0];
        float br = tr[kl*4+1], bi = ti[kl*4+1];
        float cr = tr[kl*4+2], ci = ti[kl*4+2];
        float dr = tr[kl*4+3], di = ti[kl*4+3];
        float sacr = ar+cr, saci = ai+ci;
        float dacr = ar-cr, daci = ai-ci;
        float sbdr = br+dr, sbdi = bi+di;
        float dbdr = br-dr, dbdi = bi-di;
        xr[kl+0]  = sacr + sbdr;      xi[kl+0]  = saci + sbdi;
        xr[kl+4]  = dacr - SGN*dbdi;  xi[kl+4]  = daci + SGN*dbdr;
        if (MODE != 2) {
            xr[kl+8]  = sacr - sbdr;      xi[kl+8]  = saci - sbdi;
            xr[kl+12] = dacr + SGN*dbdi;  xi[kl+12] = daci - SGN*dbdr;
        }
    }
}

__device__ __forceinline__ void cmul(float& xr_, float& xi_, float wr, float wi) {
    float pr = xr_, pi = xi_;
    xr_ = pr*wr - pi*wi;
    xi_ = pr*wi + pi*wr;
}

// apply w^k (k=1..15); log-depth product tree (depth 4 vs serial 15)
__device__ __forceinline__ void twiddle_apply(float* xr, float* xi, float w1r, float w1i) {
    float w2r = w1r*w1r - w1i*w1i, w2i = 2.0f*w1r*w1i;
    float w4r = w2r*w2r - w2i*w2i, w4i = 2.0f*w2r*w2i;
    float w8r = w4r*w4r - w4i*w4i, w8i = 2.0f*w4r*w4i;
    float w3r = w2r*w1r - w2i*w1i, w3i = w2r*w1i + w2i*w1r;
    float w5r = w4r*w1r - w4i*w1i, w5i = w4r*w1i + w4i*w1r;
    float w6r = w4r*w2r - w4i*w2i, w6i = w4r*w2i + w4i*w2r;
    float w7r = w4r*w3r - w4i*w3i, w7i = w4r*w3i + w4i*w3r;
    cmul(xr[1],  xi[1],  w1r, w1i);
    cmul(xr[2],  xi[2],  w2r, w2i);
    cmul(xr[3],  xi[3],  w3r, w3i);
    cmul(xr[4],  xi[4],  w4r, w4i);
    cmul(xr[5],  xi[5],  w5r, w5i);
    cmul(xr[6],  xi[6],  w6r, w6i);
    cmul(xr[7],  xi[7],  w7r, w7i);
    cmul(xr[8],  xi[8],  w8r, w8i);
    float wr, wi;
    wr = w8r*w1r - w8i*w1i; wi = w8r*w1i + w8i*w1r; cmul(xr[9],  xi[9],  wr, wi);
    wr = w8r*w2r - w8i*w2i; wi = w8r*w2i + w8i*w2r; cmul(xr[10], xi[10], wr, wi);
    wr = w8r*w3r - w8i*w3i; wi = w8r*w3i + w8i*w3r; cmul(xr[11], xi[11], wr, wi);
    wr = w8r*w4r - w8i*w4i; wi = w8r*w4i + w8i*w4r; cmul(xr[12], xi[12], wr, wi);
    wr = w8r*w5r - w8i*w5i; wi = w8r*w5i + w8i*w5r; cmul(xr[13], xi[13], wr, wi);
    wr = w8r*w6r - w8i*w6i; wi = w8r*w6i + w8i*w6r; cmul(xr[14], xi[14], wr, wi);
    wr = w8r*w7r - w8i*w7i; wi = w8r*w7i + w8i*w7r; cmul(xr[15], xi[15], wr, wi);
}

// forward 4096-pt FFT (input zero-padded above 2048): regs in = x[n1*256+t] (reg n1),
// out = X[k1+16k2+256k3] at reg k3, thread t = 16*k1+k2 (sigma-slot s = 256*k3+t)
__device__ __forceinline__ void fft4096_fwd_reg(float* xr, float* xi, float* lre, float* lim, int t) {
    dft16<false, 1>(xr, xi);
    float rv = (float)t * (1.0f/4096.0f);
    float w1r = cos_rev(rv), w1i = -sin_rev(rv);
    twiddle_apply(xr, xi, w1r, w1i);
    #pragma unroll
    for (int k = 0; k < 16; ++k) { int idx = XP(k*256 + t); lre[idx] = xr[k]; lim[idx] = xi[k]; }
    __syncthreads();
    int k1 = t >> 4, n3 = t & 15;
    #pragma unroll
    for (int n2 = 0; n2 < 16; ++n2) {
        int idx = XP(k1*256 + n2*16 + n3);
        xr[n2] = lre[idx]; xi[n2] = lim[idx];
    }
    dft16<false, 0>(xr, xi);
    rv = (float)n3 * (1.0f/256.0f);
    w1r = cos_rev(rv); w1i = -sin_rev(rv);
    twiddle_apply(xr, xi, w1r, w1i);
    __syncthreads();
    #pragma unroll
    for (int k = 0; k < 16; ++k) { int idx = XP(k1*256 + k*16 + n3); lre[idx] = xr[k]; lim[idx] = xi[k]; }
    __syncthreads();
    int k2 = t & 15;
    #pragma unroll
    for (int n3b = 0; n3b < 16; ++n3b) {
        int idx = XP(k1*256 + k2*16 + n3b);
        xr[n3b] = lre[idx]; xi[n3b] = lim[idx];
    }
    dft16<false, 0>(xr, xi);
}

// inverse (unscaled): regs in = W at sigma-slots 256*k3+t (reg k3); out regs n1 (only 0..7 valid)
__device__ __forceinline__ void fft4096_inv_reg(float* xr, float* xi, float* lre, float* lim, int t) {
    int k1 = t >> 4, k2 = t & 15;
    dft16<true, 0>(xr, xi);
    float rv = (float)k2 * (1.0f/256.0f);
    float w1r = cos_rev(rv), w1i = sin_rev(rv);
    twiddle_apply(xr, xi, w1r, w1i);
    __syncthreads();
    #pragma unroll
    for (int k = 0; k < 16; ++k) { int idx = XP(k1*256 + k2*16 + k); lre[idx] = xr[k]; lim[idx] = xi[k]; }
    __syncthreads();
    int n3 = t & 15;
    #pragma unroll
    for (int c = 0; c < 16; ++c) {
        int idx = XP(k1*256 + c*16 + n3);
        xr[c] = lre[idx]; xi[c] = lim[idx];
    }
    dft16<true, 0>(xr, xi);
    __syncthreads();
    #pragma unroll
    for (int k = 0; k < 16; ++k) { int idx = XP(k1*256 + k*16 + n3); lre[idx] = xr[k]; lim[idx] = xi[k]; }
    __syncthreads();
    #pragma unroll
    for (int k = 0; k < 16; ++k) {
        int idx = XP(k*256 + t);
        xr[k] = lre[idx]; xi[k] = lim[idx];
    }
    rv = (float)t * (1.0f/4096.0f);
    w1r = cos_rev(rv); w1i = sin_rev(rv);
    twiddle_apply(xr, xi, w1r, w1i);
    dft16<true, 2>(xr, xi);
}

// ---------------- kernel 0: count zeros per batch ----------------
__global__ void count_kernel(const float* __restrict__ mask, int* __restrict__ cz) {
    int b = blockIdx.x;
    int t = threadIdx.x;
    float s = 0.0f;
    for (int j = t; j < S_; j += 256) s += 1.0f - mask[b*S_ + j];
    for (int off = 32; off; off >>= 1) s += __shfl_xor(s, off);
    __shared__ float red[4];
    if ((t & 63) == 0) red[t >> 6] = s;
    __syncthreads();
    if (t == 0) {
        float tot = red[0] + red[1] + red[2] + red[3];
        cz[b] = (int)(tot + 0.5f);
    }
}

// ---------------- kernel 1: W_glu (K,N) f32 -> Wt (N,K) bf16 ----------------
__global__ void wprep_kernel(const float* __restrict__ W, unsigned short* __restrict__ Wt) {
    int idx = blockIdx.x * 256 + threadIdx.x;
    int n = idx >> 9, k = idx & 511;
    Wt[idx] = f2bf(W[k*H_ + n]);
}

// ---------------- kernel 2: kernel spectra (2ch packed, sigma order, 1/N folded) ----------------
__global__ __launch_bounds__(256) void kfft_kernel(
        const float* __restrict__ log_dt, const float* __restrict__ log_A_real,
        const float* __restrict__ A_imag,
        const float* __restrict__ B_re, const float* __restrict__ B_im,
        const float* __restrict__ C_re, const float* __restrict__ C_im,
        float4* __restrict__ Kout) {
    int hp = blockIdx.x, t = threadIdx.x;
    int h0 = hp * 2;
    __shared__ float lre[N2 + N2/16];
    __shared__ float lim[N2 + N2/16];
    __shared__ float thrv[2][NS_], lnr2[2][NS_], ctr[2][NS_], cti[2][NS_];
    __shared__ float stpr[2][NS_], stpi[2][NS_];

    if (t < 128) {
        int ch = t >> 6, n = t & 63, h = h0 + ch;
        float dt = expf(log_dt[h]);
        float Ar = -expf(log_A_real[h*NS_ + n]);
        float Ai = A_imag[h*NS_ + n];
        float drr = 1.0f - 0.5f*dt*Ar, dii = -0.5f*dt*Ai;
        float nr = 1.0f + 0.5f*dt*Ar, ni =  0.5f*dt*Ai;
        float den = drr*drr + dii*dii;
        float dAr = (nr*drr + ni*dii) / den;
        float dAi = (ni*drr - nr*dii) / den;
        float cr = C_re[h*NS_+n], ci = C_im[h*NS_+n];
        float br = B_re[h*NS_+n], bi = B_im[h*NS_+n];
        float pr = (cr*br - ci*bi) * dt, pi = (cr*bi + ci*br) * dt;
        float qr = (pr*drr + pi*dii) / den;
        float qi = (pi*drr - pr*dii) / den;
        float trv = atan2f(dAi, dAr) * 0.15915494309189535f;   // theta / 2pi
        float l2  = 0.5f * log2f(dAr*dAr + dAi*dAi);           // log2|dA|
        thrv[ch][n] = trv; lnr2[ch][n] = l2;
        ctr[ch][n] = qr;   cti[ch][n] = qi;
        float ms = __builtin_exp2f(l2 * 256.0f);
        float rv = trv * 256.0f; rv -= floorf(rv);
        stpr[ch][n] = ms * cos_rev(rv);
        stpi[ch][n] = ms * sin_rev(rv);
    }
    __syncthreads();

    float xr[16], xi[16];
    #pragma unroll
    for (int j = 0; j < 16; ++j) { xr[j] = 0.0f; xi[j] = 0.0f; }

    float tf = (float)t;
    #pragma unroll
    for (int ch = 0; ch < 2; ++ch) {
        for (int n = 0; n < NS_; ++n) {
            float trv = thrv[ch][n], l2 = lnr2[ch][n];
            float f = trv * tf; f -= floorf(f);
            float mag = __builtin_exp2f(l2 * tf);
            float vr = mag * cos_rev(f);
            float vi = mag * sin_rev(f);
            float sr = stpr[ch][n], si = stpi[ch][n];
            float cr = ctr[ch][n],  ci = cti[ch][n];
            #pragma unroll
            for (int j = 0; j < 8; ++j) {
                float contrib = cr*vr - ci*vi;
                if (ch == 0) xr[j] += contrib; else xi[j] += contrib;
                float nvr = vr*sr - vi*si;
                vi = vr*si + vi*sr;
                vr = nvr;
            }
        }
    }
    #pragma unroll
    for (int j = 0; j < 8; ++j) { xr[j] *= 2.0f; xi[j] *= 2.0f; }

    fft4096_fwd_reg(xr, xi, lre, lim, t);

    __syncthreads();
    #pragma unroll
    for (int k = 0; k < 16; ++k) { int idx = XP(k*256 + t); lre[idx] = xr[k]; lim[idx] = xi[k]; }
    __syncthreads();

    const float scale = 1.0f / (float)N2;
    #pragma unroll
    for (int it = 0; it < 16; ++it) {
        int j = 256*it + t;
        int k = (t >> 4) + ((t & 15) << 4) + (it << 8);
        int kc = (N2 - k) & (N2 - 1);
        int j2 = ((kc >> 8) << 8) + ((kc & 15) << 4) + ((kc >> 4) & 15);
        float za = xr[it], zb = xi[it];
        float zc = lre[XP(j2)], zd = lim[XP(j2)];
        float Xr = 0.5f*(za + zc), Xi2 = 0.5f*(zb - zd);
        float Yr = 0.5f*(zb + zd), Yi = 0.5f*(zc - za);
        Kout[(size_t)hp*N2 + j] = make_float4(Xr*scale, Xi2*scale, Yr*scale, Yi*scale);
    }
}

// ---------------- kernel 3: LayerNorm -> zf (B, D, S) f32, forward half only ----------------
__global__ __launch_bounds__(256) void ln_kernel(
        const float* __restrict__ x, const float* __restrict__ gamma,
        const float* __restrict__ beta, float* __restrict__ zf) {
    int blk = blockIdx.x;
    int b = blk >> 6;
    int s0 = (blk & 63) * 32;
    int t = threadIdx.x;
    int lane = t & 63, wave = t >> 6;
    __shared__ float st[32][257];

    float4 g4  = *(const float4*)(gamma + lane*4);
    float4 be4 = *(const float4*)(beta  + lane*4);
    for (int q = 0; q < 8; ++q) {
        int row = wave*8 + q;
        int s = s0 + row;
        float4 v = *(const float4*)(x + ((size_t)(b*S_ + s))*D_ + lane*4);
        float sum = v.x + v.y + v.z + v.w;
        float ss  = v.x*v.x + v.y*v.y + v.z*v.z + v.w*v.w;
        for (int off = 32; off; off >>= 1) {
            sum += __shfl_xor(sum, off);
            ss  += __shfl_xor(ss, off);
        }
        float mean = sum * (1.0f/(float)D_);
        float var  = ss  * (1.0f/(float)D_) - mean*mean;
        float rstd = rsqrtf(var + 1e-5f);
        st[row][lane*4+0] = (v.x - mean)*rstd*g4.x + be4.x;
        st[row][lane*4+1] = (v.y - mean)*rstd*g4.y + be4.y;
        st[row][lane*4+2] = (v.z - mean)*rstd*g4.z + be4.z;
        st[row][lane*4+3] = (v.w - mean)*rstd*g4.w + be4.w;
    }
    __syncthreads();
    int s_off = t & 31, dg = t >> 5;
    int s = s0 + s_off;
    for (int i = 0; i < 32; ++i) {
        int d = dg + 8*i;
        zf[((size_t)(b*D_ + d))*S_ + s] = st[s_off][d];
    }
}

// ---------------- kernel 4: packed FFT conv + D_skip + gelu -> ybf bf16 ----------------
// Backward channels (h0 >= 256) read the forward row through the reversal index.
__global__ __launch_bounds__(256) void fftconv_kernel(
        const float* __restrict__ zf, const float4* __restrict__ Kf4,
        const float* __restrict__ D_skip, const int* __restrict__ cz,
        unsigned short* __restrict__ ybf) {
    int blk = blockIdx.x;
    int b  = blk >> 8;
    int hp = blk & 255;
    int h0 = hp * 2;
    int t = threadIdx.x;
    __shared__ float lre[N2 + N2/16];
    __shared__ float lim[N2 + N2/16];

    bool back = (h0 >= D_);
    int czb = cz[b];
    const float* zrow1 = zf + ((size_t)(b*D_ + (h0 & (D_-1))))*S_;
    const float* zrow2 = zrow1 + S_;

    float xr[16], xi[16];
    float z1r[8], z2r[8];
    #pragma unroll
    for (int j = 0; j < 8; ++j) {
        int s = t + 256*j;
        int p = s;
        if (back) { p = 2*S_ - 1 - czb - s; if (p >= S_) p -= S_; }
        float v1 = zrow1[p], v2 = zrow2[p];
        z1r[j] = v1; z2r[j] = v2;
        xr[j] = v1;  xi[j] = v2;
        xr[j+8] = 0.0f; xi[j+8] = 0.0f;
    }

    fft4096_fwd_reg(xr, xi, lre, lim, t);

    __syncthreads();
    #pragma unroll
    for (int k = 0; k < 16; ++k) { int idx = XP(k*256 + t); lre[idx] = xr[k]; lim[idx] = xi[k]; }
    __syncthreads();

    const float4* kp = Kf4 + (size_t)hp * N2;
    #pragma unroll
    for (int it = 0; it < 16; ++it) {
        int j = 256*it + t;
        int k = (t >> 4) + ((t & 15) << 4) + (it << 8);
        int kc = (N2 - k) & (N2 - 1);
        int j2 = ((kc >> 8) << 8) + ((kc & 15) << 4) + ((kc >> 4) & 15);
        float za = xr[it], zb = xi[it];
        float zc = lre[XP(j2)], zd = lim[XP(j2)];
        float Xr = 0.5f*(za + zc), Xi2 = 0.5f*(zb - zd);
        float Yr = 0.5f*(zb + zd), Yi = 0.5f*(zc - za);
        float4 kk = kp[j];
        float Pr = Xr*kk.x - Xi2*kk.y, Pi = Xr*kk.y + Xi2*kk.x;
        float Qr = Yr*kk.z - Yi*kk.w,  Qi = Yr*kk.w + Yi*kk.z;
        xr[it] = Pr - Qi;
        xi[it] = Pi + Qr;
    }

    fft4096_inv_reg(xr, xi, lre, lim, t);

    float dsk1 = D_skip[h0], dsk2 = D_skip[h0+1];
    unsigned short* yb1 = ybf + ((size_t)(b*H_ + h0    ))*S_;
    unsigned short* yb2 = ybf + ((size_t)(b*H_ + h0 + 1))*S_;
    #pragma unroll
    for (int j = 0; j < 8; ++j) {
        int s = t + 256*j;
        float y1 = xr[j] + dsk1 * z1r[j];
        float y2 = xi[j] + dsk2 * z2r[j];
        yb1[s] = f2bf(gelu_f(y1));
        yb2[s] = f2bf(gelu_f(y2));
    }
}

// ---------------- kernel 5: (B,H,S)bf16 -> (B,S,H) bf16 with back-half re-reversal ----------------
__global__ __launch_bounds__(256) void transpose_kernel(
        const unsigned short* __restrict__ ybf, const int* __restrict__ cz,
        unsigned short* __restrict__ A) {
    int b  = blockIdx.z;
    int h0 = blockIdx.y * 64;
    int s0 = blockIdx.x * 64;
    int t = threadIdx.x;
    int tx = t & 63, ty = t >> 6;
    __shared__ unsigned short tile[64][65];
    bool back = (h0 >= D_);
    int czb = cz[b];
    int s = s0 + tx;
    int scol = back ? ((2*S_ - 1 - czb - s) % S_) : s;
    for (int i = 0; i < 16; ++i) {
        int hh = ty*16 + i;
        tile[hh][tx] = ybf[((size_t)(b*H_ + h0 + hh))*S_ + scol];
    }
    __syncthreads();
    for (int i = 0; i < 16; ++i) {
        int sl = ty*16 + i;
        A[((size_t)(b*S_ + s0 + sl))*H_ + h0 + tx] = tile[tx][sl];
    }
}

// ---------------- kernel 6: GLU GEMM, 128x256 tile, global_load_lds, swizzled LDS ----------------
__global__ __launch_bounds__(256) void glu_gemm_kernel(
        const unsigned short* __restrict__ A, const unsigned short* __restrict__ Wt,
        const float* __restrict__ bglu, const float* __restrict__ x,
        float* __restrict__ out) {
    int m0 = blockIdx.x * 128;
    int nh = blockIdx.y;              // which 128 d-cols
    int t = threadIdx.x;
    int lane = t & 63, w = t >> 6;
    __shared__ __align__(16) unsigned short Ab[2][4096];   // 128 rows x 32 k (swizzled)
    __shared__ __align__(16) unsigned short Bb[2][8192];   // 256 rows x 32 k (swizzled)

    f32x4 acc[2][16];
    #pragma unroll
    for (int mf = 0; mf < 2; ++mf)
        #pragma unroll
        for (int nf = 0; nf < 16; ++nf)
            acc[mf][nf] = (f32x4){0.0f, 0.0f, 0.0f, 0.0f};

    int r = t >> 2;                 // 0..63
    int kch = (t & 3) * 8;
    int wbase = (t >> 6) * 1024;

    auto stage = [&](int buf, int kk) {
        #pragma unroll
        for (int i = 0; i < 2; ++i) {
            int row = i*64 + r;
            int kel = kch ^ (((row >> 2) & 3) << 3);
            const unsigned short* src = A + ((size_t)(m0 + row))*H_ + kk + kel;
            char* dst = (char*)&Ab[buf][0] + i*4096 + wbase;
            __builtin_amdgcn_global_load_lds((const __attribute__((address_space(1))) void*)src,
                                             (__attribute__((address_space(3))) void*)dst, 16, 0, 0);
        }
        #pragma unroll
        for (int i = 0; i < 4; ++i) {
            int rb = i*64 + r;
            int n = nh*128 + rb + (rb & 128);
            int kel = kch ^ (((rb >> 2) & 3) << 3);
            const unsigned short* src = Wt + ((size_t)n)*H_ + kk + kel;
            char* dst = (char*)&Bb[buf][0] + i*4096 + wbase;
            __builtin_amdgcn_global_load_lds((const __attribute__((address_space(1))) void*)src,
                                             (__attribute__((address_space(3))) void*)dst, 16, 0, 0);
        }
    };

    int lr = lane & 15, ksel = lane >> 4;
    stage(0, 0);
    __syncthreads();

    #pragma unroll 1
    for (int step = 0; step < 16; ++step) {
        int cur = step & 1;
        if (step < 15) stage(cur ^ 1, (step + 1) * 32);
        const char* pa = (const char*)&Ab[cur][0];
        const char* pb = (const char*)&Bb[cur][0];
        bf16x8 af[2];
        #pragma unroll
        for (int mf = 0; mf < 2; ++mf) {
            int arow = w*32 + mf*16 + lr;
            af[mf] = *(const bf16x8*)(pa + arow*64 + ((ksel*16) ^ (((arow >> 2) & 3) << 4)));
        }
        #pragma unroll
        for (int nf = 0; nf < 16; ++nf) {
            int brow = nf*16 + lr;
            bf16x8 bv = *(const bf16x8*)(pb + brow*64 + ((ksel*16) ^ (((brow >> 2) & 3) << 4)));
            acc[0][nf] = __builtin_amdgcn_mfma_f32_16x16x32_bf16(af[0], bv, acc[0][nf], 0, 0, 0);
            acc[1][nf] = __builtin_amdgcn_mfma_f32_16x16x32_bf16(af[1], bv, acc[1][nf], 0, 0, 0);
        }
        __syncthreads();
    }

    int r4 = (lane >> 4) * 4;
    #pragma unroll
    for (int mf = 0; mf < 2; ++mf) {
        #pragma unroll
        for (int nf = 0; nf < 8; ++nf) {
            int tc = nf*16 + lr;
            int dcol = nh*128 + tc;
            float ba = bglu[dcol];
            float bb = bglu[256 + dcol];
            #pragma unroll
            for (int rr = 0; rr < 4; ++rr) {
                int row = w*32 + mf*16 + r4 + rr;
                size_t mi = (size_t)(m0 + row);
                float av = acc[mf][nf][rr] + ba;
                float bv = acc[mf][nf+8][rr] + bb;
                float sig = 1.0f / (1.0f + __builtin_exp2f(-1.4426950408889634f * bv));
                out[mi*D_ + dcol] = av*sig + x[mi*D_ + dcol];
            }
        }
    }
}

// ---------------- launch ----------------
extern "C" void kernel_launch(void* const* d_in, const int* in_sizes, int n_in,
                              void* d_out, int out_size, void* d_ws, size_t ws_size,
                              hipStream_t stream) {
    const float* x         = (const float*)d_in[0];
    const float* mask      = (const float*)d_in[1];
    const float* log_dt    = (const float*)d_in[2];
    const float* log_A_real= (const float*)d_in[3];
    const float* A_imag    = (const float*)d_in[4];
    const float* B_re      = (const float*)d_in[5];
    const float* B_im      = (const float*)d_in[6];
    const float* C_re      = (const float*)d_in[7];
    const float* C_im      = (const float*)d_in[8];
    const float* D_skip    = (const float*)d_in[9];
    const float* W_glu     = (const float*)d_in[10];
    const float* b_glu     = (const float*)d_in[11];
    const float* ln_gamma  = (const float*)d_in[12];
    const float* ln_beta   = (const float*)d_in[13];
    float* out = (float*)d_out;

    char* ws = (char*)d_ws;
    // cz 256B | zf 32MB (f32, fwd only) | ybf 32MB bf16 | Kf 16MB | Abf 32MB | Wt 0.5MB
    int*            cz  = (int*)ws;
    float*          zf  = (float*)(ws + 256);
    unsigned short* ybf = (unsigned short*)(ws + 256 + 33554432);
    float4*         Kf  = (float4*)(ws + 256 + 67108864);
    unsigned short* Abf = (unsigned short*)(ws + 256 + 83886080);
    unsigned short* Wt  = (unsigned short*)(ws + 256 + 117440512);

    count_kernel<<<B_, 256, 0, stream>>>(mask, cz);
    wprep_kernel<<<(H_*H_)/256, 256, 0, stream>>>(W_glu, Wt);
    kfft_kernel<<<H_/2, 256, 0, stream>>>(log_dt, log_A_real, A_imag, B_re, B_im, C_re, C_im, Kf);
    ln_kernel<<<B_*(S_/32), 256, 0, stream>>>(x, ln_gamma, ln_beta, zf);
    fftconv_kernel<<<B_*(H_/2), 256, 0, stream>>>(zf, (const float4*)Kf, D_skip, cz, ybf);
    transpose_kernel<<<dim3(S_/64, H_/64, B_), 256, 0, stream>>>(ybf, cz, Abf);
    glu_gemm_kernel<<<dim3(M_/128, 2), 256, 0, stream>>>(Abf, Wt, b_glu, x, out);
}

// Round 7
// 286.407 us; speedup vs baseline: 1.0698x; 1.0698x over previous
//
#include <hip/hip_runtime.h>
#include <hip/hip_bf16.h>
#include <math.h>

#define B_ 16
#define S_ 2048
#define D_ 256
#define H_ 512
#define NS_ 64
#define N2 4096
#define M_ (B_*S_)
#define XP2(i) ((i) + ((i) >> 4))

typedef float f32x4 __attribute__((ext_vector_type(4)));
typedef short bf16x8 __attribute__((ext_vector_type(8)));

__device__ __forceinline__ unsigned short f2bf(float x) {
    __hip_bfloat16 h = __float2bfloat16(x);
    return *reinterpret_cast<unsigned short*>(&h);
}

__device__ __forceinline__ float gelu_f(float y) {
    float u = y + 0.044715f*y*y*y;
    return y / (1.0f + __builtin_exp2f(-2.3022082f * u));
}

// hw trig on revolutions (inputs pre-reduced to [0,1))
__device__ __forceinline__ float cos_rev(float r) { return __builtin_amdgcn_cosf(r); }
__device__ __forceinline__ float sin_rev(float r) { return __builtin_amdgcn_sinf(r); }

// ---------------- 16-point DFT in registers (2 x radix-4) ----------------
// MODE 0: full.  MODE 1: inputs 8..15 are zero.  MODE 2: only outputs 0..7 needed.
template<bool INV, int MODE>
__device__ __forceinline__ void dft16(float* xr, float* xi) {
    const float SGN = INV ? 1.0f : -1.0f;
    constexpr float W16R[4][4] = {
        {1.f, 1.f, 1.f, 1.f},
        {1.f,  0.92387953251128674f,  0.70710678118654757f,  0.38268343236508984f},
        {1.f,  0.70710678118654757f,  0.0f,                 -0.70710678118654746f},
        {1.f,  0.38268343236508984f, -0.70710678118654746f, -0.92387953251128674f}};
    constexpr float W16I[4][4] = {
        {0.f, 0.f, 0.f, 0.f},
        {0.f, -0.38268343236508978f, -0.70710678118654746f, -0.92387953251128674f},
        {0.f, -0.70710678118654746f, -1.0f,                 -0.70710678118654757f},
        {0.f, -0.92387953251128674f, -0.70710678118654757f,  0.38268343236508967f}};
    float tr[16], ti[16];
    #pragma unroll
    for (int n0 = 0; n0 < 4; ++n0) {
        if (MODE == 1) {
            float ar = xr[n0],   ai = xi[n0];
            float br = xr[n0+4], bi = xi[n0+4];
            tr[0*4+n0] = ar + br;        ti[0*4+n0] = ai + bi;
            tr[2*4+n0] = ar - br;        ti[2*4+n0] = ai - bi;
            tr[1*4+n0] = ar - SGN*bi;    ti[1*4+n0] = ai + SGN*br;
            tr[3*4+n0] = ar + SGN*bi;    ti[3*4+n0] = ai - SGN*br;
        } else {
            float ar = xr[n0],    ai = xi[n0];
            float br = xr[n0+4],  bi = xi[n0+4];
            float cr = xr[n0+8],  ci = xi[n0+8];
            float dr = xr[n0+12], di = xi[n0+12];
            float sacr = ar+cr, saci = ai+ci;
            float dacr = ar-cr, daci = ai-ci;
            float sbdr = br+dr, sbdi = bi+di;
            float dbdr = br-dr, dbdi = bi-di;
            tr[0*4+n0] = sacr + sbdr;      ti[0*4+n0] = saci + sbdi;
            tr[2*4+n0] = sacr - sbdr;      ti[2*4+n0] = saci - sbdi;
            tr[1*4+n0] = dacr - SGN*dbdi;  ti[1*4+n0] = daci + SGN*dbdr;
            tr[3*4+n0] = dacr + SGN*dbdi;  ti[3*4+n0] = daci - SGN*dbdr;
        }
    }
    #pragma unroll
    for (int kl = 1; kl < 4; ++kl) {
        #pragma unroll
        for (int n0 = 1; n0 < 4; ++n0) {
            float wr = W16R[kl][n0];
            float wi = INV ? -W16I[kl][n0] : W16I[kl][n0];
            float pr = tr[kl*4+n0], pi = ti[kl*4+n0];
            tr[kl*4+n0] = pr*wr - pi*wi;
            ti[kl*4+n0] = pr*wi + pi*wr;
        }
    }
    #pragma unroll
    for (int kl = 0; kl < 4; ++kl) {
        float ar = tr[kl*4+0], ai = ti[kl*4+0];
        float br = tr[kl*4+1], bi = ti[kl*4+1];
        float cr = tr[kl*4+2], ci = ti[kl*4+2];
        float dr = tr[kl*4+3], di = ti[kl*4+3];
        float sacr = ar+cr, saci = ai+ci;
        float dacr = ar-cr, daci = ai-ci;
        float sbdr = br+dr, sbdi = bi+di;
        float dbdr = br-dr, dbdi = bi-di;
        xr[kl+0]  = sacr + sbdr;      xi[kl+0]  = saci + sbdi;
        xr[kl+4]  = dacr - SGN*dbdi;  xi[kl+4]  = daci + SGN*dbdr;
        if (MODE != 2) {
            xr[kl+8]  = sacr - sbdr;      xi[kl+8]  = saci - sbdi;
            xr[kl+12] = dacr + SGN*dbdi;  xi[kl+12] = daci - SGN*dbdr;
        }
    }
}

__device__ __forceinline__ void cmul(float& xr_, float& xi_, float wr, float wi) {
    float pr = xr_, pi = xi_;
    xr_ = pr*wr - pi*wi;
    xi_ = pr*wi + pi*wr;
}

// apply w^k (k=1..15); log-depth product tree (depth 4 vs serial 15)
__device__ __forceinline__ void twiddle_apply(float* xr, float* xi, float w1r, float w1i) {
    float w2r = w1r*w1r - w1i*w1i, w2i = 2.0f*w1r*w1i;
    float w4r = w2r*w2r - w2i*w2i, w4i = 2.0f*w2r*w2i;
    float w8r = w4r*w4r - w4i*w4i, w8i = 2.0f*w4r*w4i;
    float w3r = w2r*w1r - w2i*w1i, w3i = w2r*w1i + w2i*w1r;
    float w5r = w4r*w1r - w4i*w1i, w5i = w4r*w1i + w4i*w1r;
    float w6r = w4r*w2r - w4i*w2i, w6i = w4r*w2i + w4i*w2r;
    float w7r = w4r*w3r - w4i*w3i, w7i = w4r*w3i + w4i*w3r;
    cmul(xr[1],  xi[1],  w1r, w1i);
    cmul(xr[2],  xi[2],  w2r, w2i);
    cmul(xr[3],  xi[3],  w3r, w3i);
    cmul(xr[4],  xi[4],  w4r, w4i);
    cmul(xr[5],  xi[5],  w5r, w5i);
    cmul(xr[6],  xi[6],  w6r, w6i);
    cmul(xr[7],  xi[7],  w7r, w7i);
    cmul(xr[8],  xi[8],  w8r, w8i);
    float wr, wi;
    wr = w8r*w1r - w8i*w1i; wi = w8r*w1i + w8i*w1r; cmul(xr[9],  xi[9],  wr, wi);
    wr = w8r*w2r - w8i*w2i; wi = w8r*w2i + w8i*w2r; cmul(xr[10], xi[10], wr, wi);
    wr = w8r*w3r - w8i*w3i; wi = w8r*w3i + w8i*w3r; cmul(xr[11], xi[11], wr, wi);
    wr = w8r*w4r - w8i*w4i; wi = w8r*w4i + w8i*w4r; cmul(xr[12], xi[12], wr, wi);
    wr = w8r*w5r - w8i*w5i; wi = w8r*w5i + w8i*w5r; cmul(xr[13], xi[13], wr, wi);
    wr = w8r*w6r - w8i*w6i; wi = w8r*w6i + w8i*w6r; cmul(xr[14], xi[14], wr, wi);
    wr = w8r*w7r - w8i*w7i; wi = w8r*w7i + w8i*w7r; cmul(xr[15], xi[15], wr, wi);
}

// forward 4096-pt FFT (input zero-padded above 2048): regs in = x[n1*256+t] (reg n1),
// out = X[k1+16k2+256k3] at reg k3, thread t = 16*k1+k2 (sigma-slot s = 256*k3+t)
__device__ __forceinline__ void fft4096_fwd_reg(float* xr, float* xi, float2* ld, int t) {
    dft16<false, 1>(xr, xi);
    float rv = (float)t * (1.0f/4096.0f);
    float w1r = cos_rev(rv), w1i = -sin_rev(rv);
    twiddle_apply(xr, xi, w1r, w1i);
    #pragma unroll
    for (int k = 0; k < 16; ++k) ld[XP2(k*256 + t)] = make_float2(xr[k], xi[k]);
    __syncthreads();
    int k1 = t >> 4, n3 = t & 15;
    #pragma unroll
    for (int n2 = 0; n2 < 16; ++n2) {
        float2 v = ld[XP2(k1*256 + n2*16 + n3)];
        xr[n2] = v.x; xi[n2] = v.y;
    }
    dft16<false, 0>(xr, xi);
    rv = (float)n3 * (1.0f/256.0f);
    w1r = cos_rev(rv); w1i = -sin_rev(rv);
    twiddle_apply(xr, xi, w1r, w1i);
    __syncthreads();
    #pragma unroll
    for (int k = 0; k < 16; ++k) ld[XP2(k1*256 + k*16 + n3)] = make_float2(xr[k], xi[k]);
    __syncthreads();
    int k2 = t & 15;
    #pragma unroll
    for (int n3b = 0; n3b < 16; ++n3b) {
        float2 v = ld[XP2(k1*256 + k2*16 + n3b)];
        xr[n3b] = v.x; xi[n3b] = v.y;
    }
    dft16<false, 0>(xr, xi);
}

// inverse (unscaled): regs in = W at sigma-slots 256*k3+t (reg k3); out regs n1 (only 0..7 valid)
__device__ __forceinline__ void fft4096_inv_reg(float* xr, float* xi, float2* ld, int t) {
    int k1 = t >> 4, k2 = t & 15;
    dft16<true, 0>(xr, xi);
    float rv = (float)k2 * (1.0f/256.0f);
    float w1r = cos_rev(rv), w1i = sin_rev(rv);
    twiddle_apply(xr, xi, w1r, w1i);
    __syncthreads();
    #pragma unroll
    for (int k = 0; k < 16; ++k) ld[XP2(k1*256 + k2*16 + k)] = make_float2(xr[k], xi[k]);
    __syncthreads();
    int n3 = t & 15;
    #pragma unroll
    for (int c = 0; c < 16; ++c) {
        float2 v = ld[XP2(k1*256 + c*16 + n3)];
        xr[c] = v.x; xi[c] = v.y;
    }
    dft16<true, 0>(xr, xi);
    __syncthreads();
    #pragma unroll
    for (int k = 0; k < 16; ++k) ld[XP2(k1*256 + k*16 + n3)] = make_float2(xr[k], xi[k]);
    __syncthreads();
    #pragma unroll
    for (int k = 0; k < 16; ++k) {
        float2 v = ld[XP2(k*256 + t)];
        xr[k] = v.x; xi[k] = v.y;
    }
    rv = (float)t * (1.0f/4096.0f);
    w1r = cos_rev(rv); w1i = sin_rev(rv);
    twiddle_apply(xr, xi, w1r, w1i);
    dft16<true, 2>(xr, xi);
}

// ---------------- kernel 0: count zeros per batch ----------------
__global__ void count_kernel(const float* __restrict__ mask, int* __restrict__ cz) {
    int b = blockIdx.x;
    int t = threadIdx.x;
    float s = 0.0f;
    for (int j = t; j < S_; j += 256) s += 1.0f - mask[b*S_ + j];
    for (int off = 32; off; off >>= 1) s += __shfl_xor(s, off);
    __shared__ float red[4];
    if ((t & 63) == 0) red[t >> 6] = s;
    __syncthreads();
    if (t == 0) {
        float tot = red[0] + red[1] + red[2] + red[3];
        cz[b] = (int)(tot + 0.5f);
    }
}

// ---------------- kernel 1: W_glu (K,N) f32 -> Wt (N,K) bf16, LDS tile transpose ----------------
__global__ __launch_bounds__(256) void wprep_kernel(const float* __restrict__ W,
                                                    unsigned short* __restrict__ Wt) {
    int n0 = (blockIdx.x & 7) * 64;
    int k0 = (blockIdx.x >> 3) * 64;
    int t = threadIdx.x;
    int tx = t & 63, ty = t >> 6;
    __shared__ float tile[64][65];
    #pragma unroll
    for (int i = 0; i < 16; ++i) {
        int krow = ty*16 + i;
        tile[krow][tx] = W[(size_t)(k0 + krow)*H_ + n0 + tx];
    }
    __syncthreads();
    #pragma unroll
    for (int i = 0; i < 16; ++i) {
        int nrow = ty*16 + i;
        Wt[(size_t)(n0 + nrow)*H_ + k0 + tx] = f2bf(tile[tx][nrow]);
    }
}

// ---------------- kernel 2: kernel spectra (2ch packed, sigma order, 1/N folded) ----------------
__global__ __launch_bounds__(256) void kfft_kernel(
        const float* __restrict__ log_dt, const float* __restrict__ log_A_real,
        const float* __restrict__ A_imag,
        const float* __restrict__ B_re, const float* __restrict__ B_im,
        const float* __restrict__ C_re, const float* __restrict__ C_im,
        float4* __restrict__ Kout) {
    int hp = blockIdx.x, t = threadIdx.x;
    int h0 = hp * 2;
    __shared__ float2 ld[N2 + N2/16];
    __shared__ float thrv[2][NS_], lnr2[2][NS_], ctr[2][NS_], cti[2][NS_];
    __shared__ float stpr[2][NS_], stpi[2][NS_];

    if (t < 128) {
        int ch = t >> 6, n = t & 63, h = h0 + ch;
        float dt = expf(log_dt[h]);
        float Ar = -expf(log_A_real[h*NS_ + n]);
        float Ai = A_imag[h*NS_ + n];
        float drr = 1.0f - 0.5f*dt*Ar, dii = -0.5f*dt*Ai;
        float nr = 1.0f + 0.5f*dt*Ar, ni =  0.5f*dt*Ai;
        float den = drr*drr + dii*dii;
        float dAr = (nr*drr + ni*dii) / den;
        float dAi = (ni*drr - nr*dii) / den;
        float cr = C_re[h*NS_+n], ci = C_im[h*NS_+n];
        float br = B_re[h*NS_+n], bi = B_im[h*NS_+n];
        float pr = (cr*br - ci*bi) * dt, pi = (cr*bi + ci*br) * dt;
        float qr = (pr*drr + pi*dii) / den;
        float qi = (pi*drr - pr*dii) / den;
        float trv = atan2f(dAi, dAr) * 0.15915494309189535f;   // theta / 2pi
        float l2  = 0.5f * log2f(dAr*dAr + dAi*dAi);           // log2|dA|
        thrv[ch][n] = trv; lnr2[ch][n] = l2;
        ctr[ch][n] = qr;   cti[ch][n] = qi;
        float ms = __builtin_exp2f(l2 * 256.0f);
        float rv = trv * 256.0f; rv -= floorf(rv);
        stpr[ch][n] = ms * cos_rev(rv);
        stpi[ch][n] = ms * sin_rev(rv);
    }
    __syncthreads();

    float xr[16], xi[16];
    #pragma unroll
    for (int j = 0; j < 16; ++j) { xr[j] = 0.0f; xi[j] = 0.0f; }

    float tf = (float)t;
    #pragma unroll
    for (int ch = 0; ch < 2; ++ch) {
        for (int n = 0; n < NS_; ++n) {
            float trv = thrv[ch][n], l2 = lnr2[ch][n];
            float f = trv * tf; f -= floorf(f);
            float mag = __builtin_exp2f(l2 * tf);
            float vr = mag * cos_rev(f);
            float vi = mag * sin_rev(f);
            float sr = stpr[ch][n], si = stpi[ch][n];
            float cr = ctr[ch][n],  ci = cti[ch][n];
            #pragma unroll
            for (int j = 0; j < 8; ++j) {
                float contrib = cr*vr - ci*vi;
                if (ch == 0) xr[j] += contrib; else xi[j] += contrib;
                float nvr = vr*sr - vi*si;
                vi = vr*si + vi*sr;
                vr = nvr;
            }
        }
    }
    #pragma unroll
    for (int j = 0; j < 8; ++j) { xr[j] *= 2.0f; xi[j] *= 2.0f; }

    fft4096_fwd_reg(xr, xi, ld, t);

    __syncthreads();
    #pragma unroll
    for (int k = 0; k < 16; ++k) ld[XP2(k*256 + t)] = make_float2(xr[k], xi[k]);
    __syncthreads();

    const float scale = 1.0f / (float)N2;
    #pragma unroll
    for (int it = 0; it < 16; ++it) {
        int j = 256*it + t;
        int k = (t >> 4) + ((t & 15) << 4) + (it << 8);
        int kc = (N2 - k) & (N2 - 1);
        int j2 = ((kc >> 8) << 8) + ((kc & 15) << 4) + ((kc >> 4) & 15);
        float za = xr[it], zb = xi[it];
        float2 v2 = ld[XP2(j2)];
        float zc = v2.x, zd = v2.y;
        float Xr = 0.5f*(za + zc), Xi2 = 0.5f*(zb - zd);
        float Yr = 0.5f*(zb + zd), Yi = 0.5f*(zc - za);
        Kout[(size_t)hp*N2 + j] = make_float4(Xr*scale, Xi2*scale, Yr*scale, Yi*scale);
    }
}

// ---------------- kernel 3: LayerNorm -> zf (B, D, S) f32, forward half only ----------------
__global__ __launch_bounds__(256) void ln_kernel(
        const float* __restrict__ x, const float* __restrict__ gamma,
        const float* __restrict__ beta, float* __restrict__ zf) {
    int blk = blockIdx.x;
    int b = blk >> 6;
    int s0 = (blk & 63) * 32;
    int t = threadIdx.x;
    int lane = t & 63, wave = t >> 6;
    __shared__ float st[32][257];

    float4 g4  = *(const float4*)(gamma + lane*4);
    float4 be4 = *(const float4*)(beta  + lane*4);
    for (int q = 0; q < 8; ++q) {
        int row = wave*8 + q;
        int s = s0 + row;
        float4 v = *(const float4*)(x + ((size_t)(b*S_ + s))*D_ + lane*4);
        float sum = v.x + v.y + v.z + v.w;
        float ss  = v.x*v.x + v.y*v.y + v.z*v.z + v.w*v.w;
        for (int off = 32; off; off >>= 1) {
            sum += __shfl_xor(sum, off);
            ss  += __shfl_xor(ss, off);
        }
        float mean = sum * (1.0f/(float)D_);
        float var  = ss  * (1.0f/(float)D_) - mean*mean;
        float rstd = rsqrtf(var + 1e-5f);
        st[row][lane*4+0] = (v.x - mean)*rstd*g4.x + be4.x;
        st[row][lane*4+1] = (v.y - mean)*rstd*g4.y + be4.y;
        st[row][lane*4+2] = (v.z - mean)*rstd*g4.z + be4.z;
        st[row][lane*4+3] = (v.w - mean)*rstd*g4.w + be4.w;
    }
    __syncthreads();
    int s_off = t & 31, dg = t >> 5;
    int s = s0 + s_off;
    for (int i = 0; i < 32; ++i) {
        int d = dg + 8*i;
        zf[((size_t)(b*D_ + d))*S_ + s] = st[s_off][d];
    }
}

// ---------------- kernel 4: packed FFT conv + D_skip + gelu -> ybf bf16 ----------------
// Backward channels (h0 >= 256) read the forward row through the reversal index.
__global__ __launch_bounds__(256) void fftconv_kernel(
        const float* __restrict__ zf, const float4* __restrict__ Kf4,
        const float* __restrict__ D_skip, const int* __restrict__ cz,
        unsigned short* __restrict__ ybf) {
    int blk = blockIdx.x;
    int b  = blk >> 8;
    int hp = blk & 255;
    int h0 = hp * 2;
    int t = threadIdx.x;
    __shared__ float2 ld[N2 + N2/16];

    bool back = (h0 >= D_);
    int czb = cz[b];
    const float* zrow1 = zf + ((size_t)(b*D_ + (h0 & (D_-1))))*S_;
    const float* zrow2 = zrow1 + S_;

    float xr[16], xi[16];
    float z1r[8], z2r[8];
    #pragma unroll
    for (int j = 0; j < 8; ++j) {
        int s = t + 256*j;
        int p = s;
        if (back) { p = 2*S_ - 1 - czb - s; if (p >= S_) p -= S_; }
        float v1 = zrow1[p], v2 = zrow2[p];
        z1r[j] = v1; z2r[j] = v2;
        xr[j] = v1;  xi[j] = v2;
        xr[j+8] = 0.0f; xi[j+8] = 0.0f;
    }

    fft4096_fwd_reg(xr, xi, ld, t);

    // prefetch first half of kernel spectrum while the exchange barriers run
    const float4* kp = Kf4 + (size_t)hp * N2;
    float4 kk0[8];
    #pragma unroll
    for (int it = 0; it < 8; ++it) kk0[it] = kp[256*it + t];

    __syncthreads();
    #pragma unroll
    for (int k = 0; k < 16; ++k) ld[XP2(k*256 + t)] = make_float2(xr[k], xi[k]);
    __syncthreads();

    float4 kk1[8];
    #pragma unroll
    for (int it = 0; it < 8; ++it) kk1[it] = kp[256*(8 + it) + t];

    #pragma unroll
    for (int it = 0; it < 8; ++it) {
        int j2;
        {
            int k = (t >> 4) + ((t & 15) << 4) + (it << 8);
            int kc = (N2 - k) & (N2 - 1);
            j2 = ((kc >> 8) << 8) + ((kc & 15) << 4) + ((kc >> 4) & 15);
        }
        float za = xr[it], zb = xi[it];
        float2 v2 = ld[XP2(j2)];
        float zc = v2.x, zd = v2.y;
        float Xr = 0.5f*(za + zc), Xi2 = 0.5f*(zb - zd);
        float Yr = 0.5f*(zb + zd), Yi = 0.5f*(zc - za);
        float4 kk = kk0[it];
        float Pr = Xr*kk.x - Xi2*kk.y, Pi = Xr*kk.y + Xi2*kk.x;
        float Qr = Yr*kk.z - Yi*kk.w,  Qi = Yr*kk.w + Yi*kk.z;
        xr[it] = Pr - Qi;
        xi[it] = Pi + Qr;
    }
    #pragma unroll
    for (int it = 8; it < 16; ++it) {
        int j2;
        {
            int k = (t >> 4) + ((t & 15) << 4) + (it << 8);
            int kc = (N2 - k) & (N2 - 1);
            j2 = ((kc >> 8) << 8) + ((kc & 15) << 4) + ((kc >> 4) & 15);
        }
        float za = xr[it], zb = xi[it];
        float2 v2 = ld[XP2(j2)];
        float zc = v2.x, zd = v2.y;
        float Xr = 0.5f*(za + zc), Xi2 = 0.5f*(zb - zd);
        float Yr = 0.5f*(zb + zd), Yi = 0.5f*(zc - za);
        float4 kk = kk1[it - 8];
        float Pr = Xr*kk.x - Xi2*kk.y, Pi = Xr*kk.y + Xi2*kk.x;
        float Qr = Yr*kk.z - Yi*kk.w,  Qi = Yr*kk.w + Yi*kk.z;
        xr[it] = Pr - Qi;
        xi[it] = Pi + Qr;
    }

    fft4096_inv_reg(xr, xi, ld, t);

    float dsk1 = D_skip[h0], dsk2 = D_skip[h0+1];
    unsigned short* yb1 = ybf + ((size_t)(b*H_ + h0    ))*S_;
    unsigned short* yb2 = ybf + ((size_t)(b*H_ + h0 + 1))*S_;
    #pragma unroll
    for (int j = 0; j < 8; ++j) {
        int s = t + 256*j;
        float y1 = xr[j] + dsk1 * z1r[j];
        float y2 = xi[j] + dsk2 * z2r[j];
        yb1[s] = f2bf(gelu_f(y1));
        yb2[s] = f2bf(gelu_f(y2));
    }
}

// ---------------- kernel 5: (B,H,S)bf16 -> (B,S,H) bf16 with back-half re-reversal ----------------
__global__ __launch_bounds__(256) void transpose_kernel(
        const unsigned short* __restrict__ ybf, const int* __restrict__ cz,
        unsigned short* __restrict__ A) {
    int b  = blockIdx.z;
    int h0 = blockIdx.y * 64;
    int s0 = blockIdx.x * 64;
    int t = threadIdx.x;
    int tx = t & 63, ty = t >> 6;
    __shared__ unsigned short tile[64][65];
    bool back = (h0 >= D_);
    int czb = cz[b];
    int s = s0 + tx;
    int scol = back ? ((2*S_ - 1 - czb - s) % S_) : s;
    for (int i = 0; i < 16; ++i) {
        int hh = ty*16 + i;
        tile[hh][tx] = ybf[((size_t)(b*H_ + h0 + hh))*S_ + scol];
    }
    __syncthreads();
    for (int i = 0; i < 16; ++i) {
        int sl = ty*16 + i;
        A[((size_t)(b*S_ + s0 + sl))*H_ + h0 + tx] = tile[tx][sl];
    }
}

// ---------------- kernel 6: GLU GEMM, 128x256 tile, global_load_lds, swizzled LDS ----------------
__global__ __launch_bounds__(256) void glu_gemm_kernel(
        const unsigned short* __restrict__ A, const unsigned short* __restrict__ Wt,
        const float* __restrict__ bglu, const float* __restrict__ x,
        float* __restrict__ out) {
    int m0 = blockIdx.x * 128;
    int nh = blockIdx.y;              // which 128 d-cols
    int t = threadIdx.x;
    int lane = t & 63, w = t >> 6;
    __shared__ __align__(16) unsigned short Ab[2][4096];   // 128 rows x 32 k (swizzled)
    __shared__ __align__(16) unsigned short Bb[2][8192];   // 256 rows x 32 k (swizzled)

    f32x4 acc[2][16];
    #pragma unroll
    for (int mf = 0; mf < 2; ++mf)
        #pragma unroll
        for (int nf = 0; nf < 16; ++nf)
            acc[mf][nf] = (f32x4){0.0f, 0.0f, 0.0f, 0.0f};

    int r = t >> 2;                 // 0..63
    int kch = (t & 3) * 8;
    int wbase = (t >> 6) * 1024;

    auto stage = [&](int buf, int kk) {
        #pragma unroll
        for (int i = 0; i < 2; ++i) {
            int row = i*64 + r;
            int kel = kch ^ (((row >> 2) & 3) << 3);
            const unsigned short* src = A + ((size_t)(m0 + row))*H_ + kk + kel;
            char* dst = (char*)&Ab[buf][0] + i*4096 + wbase;
            __builtin_amdgcn_global_load_lds((const __attribute__((address_space(1))) void*)src,
                                             (__attribute__((address_space(3))) void*)dst, 16, 0, 0);
        }
        #pragma unroll
        for (int i = 0; i < 4; ++i) {
            int rb = i*64 + r;
            int n = nh*128 + rb + (rb & 128);
            int kel = kch ^ (((rb >> 2) & 3) << 3);
            const unsigned short* src = Wt + ((size_t)n)*H_ + kk + kel;
            char* dst = (char*)&Bb[buf][0] + i*4096 + wbase;
            __builtin_amdgcn_global_load_lds((const __attribute__((address_space(1))) void*)src,
                                             (__attribute__((address_space(3))) void*)dst, 16, 0, 0);
        }
    };

    int lr = lane & 15, ksel = lane >> 4;
    stage(0, 0);
    __syncthreads();

    #pragma unroll 1
    for (int step = 0; step < 16; ++step) {
        int cur = step & 1;
        if (step < 15) stage(cur ^ 1, (step + 1) * 32);
        const char* pa = (const char*)&Ab[cur][0];
        const char* pb = (const char*)&Bb[cur][0];
        bf16x8 af[2];
        #pragma unroll
        for (int mf = 0; mf < 2; ++mf) {
            int arow = w*32 + mf*16 + lr;
            af[mf] = *(const bf16x8*)(pa + arow*64 + ((ksel*16) ^ (((arow >> 2) & 3) << 4)));
        }
        #pragma unroll
        for (int nf = 0; nf < 16; ++nf) {
            int brow = nf*16 + lr;
            bf16x8 bv = *(const bf16x8*)(pb + brow*64 + ((ksel*16) ^ (((brow >> 2) & 3) << 4)));
            acc[0][nf] = __builtin_amdgcn_mfma_f32_16x16x32_bf16(af[0], bv, acc[0][nf], 0, 0, 0);
            acc[1][nf] = __builtin_amdgcn_mfma_f32_16x16x32_bf16(af[1], bv, acc[1][nf], 0, 0, 0);
        }
        __syncthreads();
    }

    int r4 = (lane >> 4) * 4;
    #pragma unroll
    for (int mf = 0; mf < 2; ++mf) {
        #pragma unroll
        for (int nf = 0; nf < 8; ++nf) {
            int tc = nf*16 + lr;
            int dcol = nh*128 + tc;
            float ba = bglu[dcol];
            float bb = bglu[256 + dcol];
            #pragma unroll
            for (int rr = 0; rr < 4; ++rr) {
                int row = w*32 + mf*16 + r4 + rr;
                size_t mi = (size_t)(m0 + row);
                float av = acc[mf][nf][rr] + ba;
                float bv = acc[mf][nf+8][rr] + bb;
                float sig = 1.0f / (1.0f + __builtin_exp2f(-1.4426950408889634f * bv));
                out[mi*D_ + dcol] = av*sig + x[mi*D_ + dcol];
            }
        }
    }
}

// ---------------- launch ----------------
extern "C" void kernel_launch(void* const* d_in, const int* in_sizes, int n_in,
                              void* d_out, int out_size, void* d_ws, size_t ws_size,
                              hipStream_t stream) {
    const float* x         = (const float*)d_in[0];
    const float* mask      = (const float*)d_in[1];
    const float* log_dt    = (const float*)d_in[2];
    const float* log_A_real= (const float*)d_in[3];
    const float* A_imag    = (const float*)d_in[4];
    const float* B_re      = (const float*)d_in[5];
    const float* B_im      = (const float*)d_in[6];
    const float* C_re      = (const float*)d_in[7];
    const float* C_im      = (const float*)d_in[8];
    const float* D_skip    = (const float*)d_in[9];
    const float* W_glu     = (const float*)d_in[10];
    const float* b_glu     = (const float*)d_in[11];
    const float* ln_gamma  = (const float*)d_in[12];
    const float* ln_beta   = (const float*)d_in[13];
    float* out = (float*)d_out;

    char* ws = (char*)d_ws;
    // cz 256B | zf 32MB (f32, fwd only) | ybf 32MB bf16 | Kf 16MB | Abf 32MB | Wt 0.5MB
    int*            cz  = (int*)ws;
    float*          zf  = (float*)(ws + 256);
    unsigned short* ybf = (unsigned short*)(ws + 256 + 33554432);
    float4*         Kf  = (float4*)(ws + 256 + 67108864);
    unsigned short* Abf = (unsigned short*)(ws + 256 + 83886080);
    unsigned short* Wt  = (unsigned short*)(ws + 256 + 117440512);

    count_kernel<<<B_, 256, 0, stream>>>(mask, cz);
    wprep_kernel<<<64, 256, 0, stream>>>(W_glu, Wt);
    kfft_kernel<<<H_/2, 256, 0, stream>>>(log_dt, log_A_real, A_imag, B_re, B_im, C_re, C_im, Kf);
    ln_kernel<<<B_*(S_/32), 256, 0, stream>>>(x, ln_gamma, ln_beta, zf);
    fftconv_kernel<<<B_*(H_/2), 256, 0, stream>>>(zf, (const float4*)Kf, D_skip, cz, ybf);
    transpose_kernel<<<dim3(S_/64, H_/64, B_), 256, 0, stream>>>(ybf, cz, Abf);
    glu_gemm_kernel<<<dim3(M_/128, 2), 256, 0, stream>>>(Abf, Wt, b_glu, x, out);
}